// Round 3
// baseline (16285.744 us; speedup 1.0000x reference)
//
#include <hip/hip_runtime.h>
#include <stdint.h>

// 4-layer LSTM (B=64,S=512,H=512) + LayerNorm + proj(512->64), fp32 in/out.
// v2: persistent pipelined kernel, ws-safe (4.2MB), fused LN+proj.
//  - 256 blocks x 256 thr; block = (layer g = bid&3, 8-col h-slice jblk=bid>>2).
//  - Weight slice stationary in REGISTERS as f16 MFMA B-frags.
//  - Waves split K: h2=0 waves consume upstream h^{l-1}[t]; h2=1 own h^l[t-1];
//    partials combined via an 8KB LDS z-tile.
//  - Cross-block sync: per-(layer,block) monotone step flags + agent fences.
//    Layers pipeline with 1-step skew (critical path ~515 steps).
//  - ALL layers (incl. 3) use 16-step rings -> hb = 4MB (no 32MB h3 slab;
//    v1b overran unknown ws_size -> late-t garbage, absmax 1.5).
//  - LN+proj fused into layer-3 blocks, sliced BY BATCH ROW (block jblk owns
//    row b=jblk): per iteration t computes out[jblk, t-1, :] from the ring.
//    Ring safety: slot (t-1)&15 overwritten first at iteration t+15, whose
//    own-layer spin (flags>=t+15) implies every block completed iteration t
//    (hence its slice of LN[t-1]) -> no extra flags needed.

#define B_    64
#define S_    512
#define DIN_  64
#define H_    512
#define DOUT_ 64
#define RING_ 16

typedef _Float16 half8 __attribute__((ext_vector_type(8)));
typedef float    f32x4 __attribute__((ext_vector_type(4)));

__device__ __forceinline__ float sigm(float x) {
  return 1.0f / (1.0f + exp2f(-1.4426950408889634f * x));
}
__device__ __forceinline__ float tanh_(float x) {
  float e = exp2f(2.8853900817779268f * x);
  return 1.0f - 2.0f / (e + 1.0f);
}

// 16-deep ring slab for every layer
__device__ __forceinline__ _Float16* slab_ptr(_Float16* hb, int l, int t) {
  return hb + ((size_t)l * RING_ + (size_t)(t & (RING_ - 1))) * (size_t)(B_ * H_);
}

// wait until all 64 flags >= val, then agent-acquire (invalidate caches)
__device__ __forceinline__ void spin_ge(const int* f, int lane, int val) {
  for (;;) {
    int v = __hip_atomic_load((int*)&f[lane], __ATOMIC_RELAXED,
                              __HIP_MEMORY_SCOPE_AGENT);
    if (__all(v >= val)) break;
    __builtin_amdgcn_s_sleep(1);
  }
  __builtin_amdgcn_fence(__ATOMIC_ACQUIRE, "agent");
}

__global__ __launch_bounds__(256, 1)
void lstm_fused(const float* __restrict__ x,
                const float* __restrict__ Wl0, const float* __restrict__ bl0,
                const float* __restrict__ Wl1, const float* __restrict__ bl1,
                const float* __restrict__ Wl2, const float* __restrict__ bl2,
                const float* __restrict__ Wl3, const float* __restrict__ bl3,
                const float* __restrict__ lng, const float* __restrict__ lnb,
                const float* __restrict__ Wo,  const float* __restrict__ bo,
                int* __restrict__ flags, _Float16* __restrict__ hb,
                float* __restrict__ out)
{
  const int tid  = threadIdx.x;
  const int lane = tid & 63;
  const int wid  = tid >> 6;
  const int m2   = wid & 1;   // M half (rows m2*32..m2*32+31)
  const int h2   = wid >> 1;  // K half
  const int bid  = blockIdx.x;
  const int g    = bid & 3;   // layer
  const int jblk = bid >> 2;  // 0..63
  const int j0   = jblk * 8;  // h-column slice base

  const float* W    = (g==0)?Wl0:(g==1)?Wl1:(g==2)?Wl2:Wl3;
  const float* bias = (g==0)?bl0:(g==1)?bl1:(g==2)?bl2:bl3;
  const int fanin = (g == 0) ? (DIN_ + H_) : (2 * H_);
  const int KKH   = (g == 0) ? 9 : 16;   // K/32 chunks per wave-half
  const int kk0   = h2 * KKH;

  int* f_own = flags + g * 64;
  const int* f_up = flags + (g > 0 ? (g - 1) * 64 : 0);
  const int* f_dn = flags + (g < 3 ? (g + 1) * 64 : 0);

  const int c16 = lane & 15;
  const int kg8 = (lane >> 4) * 8;
  const int rb0 = m2 * 32 + c16;   // A row for mt=0
  const int rb1 = rb0 + 16;        // A row for mt=1

  // ---- stationary gate-weight fragments (f16) ----
  // B-frag (kk,nt): lane holds W[n(nt,c16)][(kk0+kk)*32 + kg8 .. +7]
  // n ordering inside the 32-col slice: [i j0..j0+7 | f .. | g .. | o ..]
  half8 bw[16][2];
  #pragma unroll
  for (int kk2 = 0; kk2 < 16; ++kk2) {
    if (kk2 < KKH) {
      int kb = (kk0 + kk2) * 32 + kg8;
      #pragma unroll
      for (int nt = 0; nt < 2; ++nt) {
        int nl = nt * 16 + c16;
        int n  = (nl >> 3) * 512 + j0 + (nl & 7);
        const float* src = W + (size_t)n * fanin + kb;
        half8 r;
        #pragma unroll
        for (int e = 0; e < 8; ++e) r[e] = (_Float16)src[e];
        bw[kk2][nt] = r;
      }
    }
  }

  // ---- layer-3 extras: stationary Wo tile (f16), LN params, bias ----
  half8 wo16[16];
  float lng0 = 0.f, lng1 = 0.f, lnb0 = 0.f, lnb1 = 0.f, bo_v = 0.f;
  if (g == 3) {
    const int o = (wid << 4) + c16;          // wave's o-tile column
    #pragma unroll
    for (int kk = 0; kk < 16; ++kk) {
      const float* wp = Wo + (size_t)o * H_ + kk * 32 + kg8;
      half8 r;
      #pragma unroll
      for (int e = 0; e < 8; ++e) r[e] = (_Float16)wp[e];
      wo16[kk] = r;
    }
    lng0 = lng[2 * tid];  lng1 = lng[2 * tid + 1];
    lnb0 = lnb[2 * tid];  lnb1 = lnb[2 * tid + 1];
    bo_v = bo[o];
  }

  // ---- gate-phase constants: thread (gb = batch, gj / gj+4 = h cols) ----
  const int gb = tid & 63;
  const int gj = tid >> 6;
  const float bi0 = bias[0*512 + j0 + gj],     bf0 = bias[1*512 + j0 + gj];
  const float bg0 = bias[2*512 + j0 + gj],     bo0 = bias[3*512 + j0 + gj];
  const float bi1 = bias[0*512 + j0 + gj + 4], bf1 = bias[1*512 + j0 + gj + 4];
  const float bg1 = bias[2*512 + j0 + gj + 4], bo1 = bias[3*512 + j0 + gj + 4];
  float c0 = 0.f, c1 = 0.f;  // cell state stays in registers

  __shared__ float zl[64][33];
  __shared__ _Float16 hrow16[512];
  __shared__ float lnred[8];

  // ---- fused LN + proj slice: this block's batch row b = jblk, step t_ln ----
  auto ln_slice = [&](int t_ln) {
    __builtin_amdgcn_fence(__ATOMIC_ACQUIRE, "agent");
    const _Float16* hp = slab_ptr(hb, 3, t_ln) + (size_t)jblk * H_ + 2 * tid;
    float v0 = (float)hp[0], v1 = (float)hp[1];
    float s = v0 + v1, q = v0 * v0 + v1 * v1;
    #pragma unroll
    for (int d = 1; d < 64; d <<= 1) {
      s += __shfl_xor(s, d);
      q += __shfl_xor(q, d);
    }
    if (lane == 0) { lnred[wid * 2] = s; lnred[wid * 2 + 1] = q; }
    __syncthreads();
    float ss = lnred[0] + lnred[2] + lnred[4] + lnred[6];
    float qq = lnred[1] + lnred[3] + lnred[5] + lnred[7];
    float mu = ss * (1.f / 512.f);
    float rs = rsqrtf(qq * (1.f / 512.f) - mu * mu + 1e-5f);
    hrow16[2 * tid]     = (_Float16)((v0 - mu) * rs * lng0 + lnb0);
    hrow16[2 * tid + 1] = (_Float16)((v1 - mu) * rs * lng1 + lnb1);
    __syncthreads();
    // proj via MFMA: A row 0 = normalized h-row, other rows zero
    f32x4 pacc = {};
    #pragma unroll
    for (int kk = 0; kk < 16; ++kk) {
      half8 a = {};
      if (c16 == 0) a = *(const half8*)(hrow16 + kk * 32 + kg8);
      pacc = __builtin_amdgcn_mfma_f32_16x16x32_f16(a, wo16[kk], pacc, 0,0,0);
    }
    if (lane < 16) {   // D[0][c16] lives in lanes 0..15, reg 0
      out[((size_t)jblk * S_ + t_ln) * DOUT_ + (wid << 4) + lane]
          = pacc[0] + bo_v;
    }
  };

  for (int t = 0; t < S_; ++t) {
    f32x4 acc00 = {}, acc01 = {}, acc10 = {}, acc11 = {};

    if (g == 0) {
      if (t > 0) spin_ge(f_own, lane, t);
      const _Float16* hsl = slab_ptr(hb, 0, t - 1);
      half8 av0[9], av1[9];
      if (h2 == 0) {
        // kk 0,1 -> x (fp32, convert); kk 2..8 -> own h at hcol = kk*32-64
        #pragma unroll
        for (int kk2 = 0; kk2 < 2; ++kk2) {
          int kcol = kk2 * 32 + kg8;
          const float* xp0 = x + ((size_t)rb0 * S_ + t) * DIN_ + kcol;
          const float* xp1 = x + ((size_t)rb1 * S_ + t) * DIN_ + kcol;
          half8 a0, a1;
          #pragma unroll
          for (int e = 0; e < 8; ++e) {
            a0[e] = (_Float16)xp0[e]; a1[e] = (_Float16)xp1[e];
          }
          av0[kk2] = a0; av1[kk2] = a1;
        }
        #pragma unroll
        for (int kk2 = 2; kk2 < 9; ++kk2) {
          int hcol = kk2 * 32 + kg8 - 64;
          half8 a0 = {}, a1 = {};
          if (t > 0) {
            a0 = *(const half8*)(hsl + (size_t)rb0 * H_ + hcol);
            a1 = *(const half8*)(hsl + (size_t)rb1 * H_ + hcol);
          }
          av0[kk2] = a0; av1[kk2] = a1;
        }
      } else {
        #pragma unroll
        for (int kk2 = 0; kk2 < 9; ++kk2) {
          int hcol = (9 + kk2) * 32 + kg8 - 64;
          half8 a0 = {}, a1 = {};
          if (t > 0) {
            a0 = *(const half8*)(hsl + (size_t)rb0 * H_ + hcol);
            a1 = *(const half8*)(hsl + (size_t)rb1 * H_ + hcol);
          }
          av0[kk2] = a0; av1[kk2] = a1;
        }
      }
      #pragma unroll
      for (int kk2 = 0; kk2 < 9; ++kk2) {
        acc00 = __builtin_amdgcn_mfma_f32_16x16x32_f16(av0[kk2], bw[kk2][0], acc00, 0,0,0);
        acc01 = __builtin_amdgcn_mfma_f32_16x16x32_f16(av0[kk2], bw[kk2][1], acc01, 0,0,0);
        acc10 = __builtin_amdgcn_mfma_f32_16x16x32_f16(av1[kk2], bw[kk2][0], acc10, 0,0,0);
        acc11 = __builtin_amdgcn_mfma_f32_16x16x32_f16(av1[kk2], bw[kk2][1], acc11, 0,0,0);
      }
    } else {
      // h2=0 waves: upstream h^{g-1}[t]; h2=1: own h^g[t-1]
      if (h2 == 0) spin_ge(f_up, lane, t + 1);
      else if (t > 0) spin_ge(f_own, lane, t);
      const _Float16* src = (h2 == 0) ? slab_ptr(hb, g - 1, t)
                                      : slab_ptr(hb, g, t - 1);
      const bool zero = (h2 == 1) && (t == 0);
      half8 av0[16], av1[16];
      if (!zero) {
        #pragma unroll
        for (int kk2 = 0; kk2 < 16; ++kk2) {
          int kcol = kk2 * 32 + kg8;
          av0[kk2] = *(const half8*)(src + (size_t)rb0 * H_ + kcol);
          av1[kk2] = *(const half8*)(src + (size_t)rb1 * H_ + kcol);
        }
      } else {
        #pragma unroll
        for (int kk2 = 0; kk2 < 16; ++kk2) { av0[kk2] = {}; av1[kk2] = {}; }
      }
      #pragma unroll
      for (int kk2 = 0; kk2 < 16; ++kk2) {
        acc00 = __builtin_amdgcn_mfma_f32_16x16x32_f16(av0[kk2], bw[kk2][0], acc00, 0,0,0);
        acc01 = __builtin_amdgcn_mfma_f32_16x16x32_f16(av0[kk2], bw[kk2][1], acc01, 0,0,0);
        acc10 = __builtin_amdgcn_mfma_f32_16x16x32_f16(av1[kk2], bw[kk2][0], acc10, 0,0,0);
        acc11 = __builtin_amdgcn_mfma_f32_16x16x32_f16(av1[kk2], bw[kk2][1], acc11, 0,0,0);
      }
    }

    // ---- combine K-halves in LDS (C layout: col=lane&15, row=(lane>>4)*4+r)
    const int zr0 = m2 * 32 + (lane >> 4) * 4;
    if (h2 == 0) {
      #pragma unroll
      for (int r = 0; r < 4; ++r) {
        zl[zr0 + r][c16]            = acc00[r];
        zl[zr0 + r][16 + c16]       = acc01[r];
        zl[zr0 + 16 + r][c16]       = acc10[r];
        zl[zr0 + 16 + r][16 + c16]  = acc11[r];
      }
    }
    __syncthreads();
    if (h2 == 1) {
      #pragma unroll
      for (int r = 0; r < 4; ++r) {
        zl[zr0 + r][c16]            += acc00[r];
        zl[zr0 + r][16 + c16]       += acc01[r];
        zl[zr0 + 16 + r][c16]       += acc10[r];
        zl[zr0 + 16 + r][16 + c16]  += acc11[r];
      }
    }
    // ring back-pressure: don't overwrite slot t%16 until downstream did t-16
    if (g < 3 && t >= RING_) spin_ge(f_dn, lane, t - (RING_ - 1));
    __syncthreads();

    // ---- gates + cell update (fp32), h -> f16 ring ----
    _Float16* osl = slab_ptr(hb, g, t);
    {
      float zi = zl[gb][gj]      + bi0;
      float zf = zl[gb][8 + gj]  + bf0;
      float zg = zl[gb][16 + gj] + bg0;
      float zo = zl[gb][24 + gj] + bo0;
      float cc = sigm(zf) * c0 + sigm(zi) * tanh_(zg);
      c0 = cc;
      osl[(size_t)gb * H_ + j0 + gj] = (_Float16)(sigm(zo) * tanh_(cc));

      zi = zl[gb][gj + 4]      + bi1;
      zf = zl[gb][8 + gj + 4]  + bf1;
      zg = zl[gb][16 + gj + 4] + bg1;
      zo = zl[gb][24 + gj + 4] + bo1;
      cc = sigm(zf) * c1 + sigm(zi) * tanh_(zg);
      c1 = cc;
      osl[(size_t)gb * H_ + j0 + gj + 4] = (_Float16)(sigm(zo) * tanh_(cc));
    }
    __syncthreads();  // all h stores drained (vmcnt(0)) before publish
    if (tid == 0) {
      __builtin_amdgcn_fence(__ATOMIC_RELEASE, "agent");  // flush to coherent pt
      __hip_atomic_store(&f_own[jblk], t + 1, __ATOMIC_RELAXED,
                         __HIP_MEMORY_SCOPE_AGENT);
    }

    // ---- fused LN + proj for step t-1 (layer-3 blocks, own batch row) ----
    // Data-ready: h2=1 spin this iteration saw all flags >= t (peers wrote
    // h^3[t-1]); slot (t-1)&15 stays valid until peer iteration t+15, which
    // requires flags >= t+15 => our iteration t (this slice) completed.
    if (g == 3 && t >= 1) ln_slice(t - 1);
  }

  if (g == 3) {           // final step's LN+proj
    spin_ge(f_own, lane, S_);
    ln_slice(S_ - 1);
  }
}

extern "C" void kernel_launch(void* const* d_in, const int* in_sizes, int n_in,
                              void* d_out, int out_size, void* d_ws, size_t ws_size,
                              hipStream_t stream) {
  const float* x   = (const float*)d_in[0];
  const float* W0  = (const float*)d_in[1];
  const float* b0  = (const float*)d_in[2];
  const float* W1  = (const float*)d_in[3];
  const float* b1  = (const float*)d_in[4];
  const float* W2  = (const float*)d_in[5];
  const float* b2  = (const float*)d_in[6];
  const float* W3  = (const float*)d_in[7];
  const float* b3  = (const float*)d_in[8];
  const float* lng = (const float*)d_in[9];
  const float* lnb = (const float*)d_in[10];
  const float* Wo  = (const float*)d_in[11];
  const float* bo  = (const float*)d_in[12];
  float* out = (float*)d_out;

  int* flags = (int*)d_ws;                          // [4][64] step flags
  _Float16* hb = (_Float16*)((char*)d_ws + 4096);   // 4 x 16-slot rings, 4MB

  hipMemsetAsync(flags, 0, 4096, stream);
  hipLaunchKernelGGL(lstm_fused, dim3(256), dim3(256), 0, stream,
                     x, W0, b0, W1, b1, W2, b2, W3, b3,
                     lng, lnb, Wo, bo, flags, hb, out);
}

// Round 4
// 10746.542 us; speedup vs baseline: 1.5154x; 1.5154x over previous
//
#include <hip/hip_runtime.h>
#include <stdint.h>

// 4-layer LSTM (B=64,S=512,H=512) + LayerNorm + proj(512->64), fp32 in/out.
// v3: fence-free cross-XCD coherence.
//  - v2 passed (absmax 7.8e-3) but ran 16.3ms: per-step agent fences compile
//    to full L2 writeback/invalidate on gfx950 (non-coherent per-XCD L2) ->
//    ~10 cache-flush ops x 32 blocks/XCD per step = flush storm (47ms outliers,
//    1.6GB HBM refetch). v3 removes ALL fences: cross-block data (h rings,
//    flags) uses relaxed AGENT-scope atomic dwords (compiler emits LLC-coherent
//    loads/stores that bypass L2). Ordering: producer drains stores at the
//    pre-publish __syncthreads(); consumer loads issue after spin exit
//    (control dep + sched_barrier); LLC serializes -> flag visible => h visible.
//  - Structure unchanged: 256 blocks x 256 thr; block=(layer g, 8-col slice);
//    weights stationary in registers as f16 MFMA B-frags; waves split K;
//    16-step h rings (4.2MB ws); LN+proj fused into layer-3 blocks by batch row.

#define B_    64
#define S_    512
#define DIN_  64
#define H_    512
#define DOUT_ 64
#define RING_ 16

typedef _Float16 half8 __attribute__((ext_vector_type(8)));
typedef float    f32x4 __attribute__((ext_vector_type(4)));

__device__ __forceinline__ float sigm(float x) {
  return 1.0f / (1.0f + exp2f(-1.4426950408889634f * x));
}
__device__ __forceinline__ float tanh_(float x) {
  float e = exp2f(2.8853900817779268f * x);
  return 1.0f - 2.0f / (e + 1.0f);
}

// 16-deep ring slab for every layer
__device__ __forceinline__ _Float16* slab_ptr(_Float16* hb, int l, int t) {
  return hb + ((size_t)l * RING_ + (size_t)(t & (RING_ - 1))) * (size_t)(B_ * H_);
}

// coherent (LLC) 16B load as 4 agent-scope relaxed atomic dwords
__device__ __forceinline__ half8 ld8c(const _Float16* p) {
  const uint32_t* q = (const uint32_t*)p;
  union { uint32_t u[4]; half8 v; } r;
  #pragma unroll
  for (int i = 0; i < 4; ++i)
    r.u[i] = __hip_atomic_load(q + i, __ATOMIC_RELAXED, __HIP_MEMORY_SCOPE_AGENT);
  return r.v;
}

// wait until all 64 flags >= val (flag i in lane i); NO cache fence.
__device__ __forceinline__ void spin_ge(const int* f, int lane, int val) {
  for (;;) {
    int v = __hip_atomic_load((int*)&f[lane], __ATOMIC_RELAXED,
                              __HIP_MEMORY_SCOPE_AGENT);
    if (__all(v >= val)) break;
    __builtin_amdgcn_s_sleep(1);
  }
  __builtin_amdgcn_sched_barrier(0);   // keep subsequent loads below the spin
}

__global__ __launch_bounds__(256, 1)
void lstm_fused(const float* __restrict__ x,
                const float* __restrict__ Wl0, const float* __restrict__ bl0,
                const float* __restrict__ Wl1, const float* __restrict__ bl1,
                const float* __restrict__ Wl2, const float* __restrict__ bl2,
                const float* __restrict__ Wl3, const float* __restrict__ bl3,
                const float* __restrict__ lng, const float* __restrict__ lnb,
                const float* __restrict__ Wo,  const float* __restrict__ bo,
                int* __restrict__ flags, _Float16* __restrict__ hb,
                float* __restrict__ out)
{
  const int tid  = threadIdx.x;
  const int lane = tid & 63;
  const int wid  = tid >> 6;
  const int m2   = wid & 1;   // M half (rows m2*32..m2*32+31)
  const int h2   = wid >> 1;  // K half
  const int bid  = blockIdx.x;
  const int g    = bid & 3;   // layer
  const int jblk = bid >> 2;  // 0..63
  const int j0   = jblk * 8;  // h-column slice base

  const float* W    = (g==0)?Wl0:(g==1)?Wl1:(g==2)?Wl2:Wl3;
  const float* bias = (g==0)?bl0:(g==1)?bl1:(g==2)?bl2:bl3;
  const int fanin = (g == 0) ? (DIN_ + H_) : (2 * H_);
  const int KKH   = (g == 0) ? 9 : 16;   // K/32 chunks per wave-half
  const int kk0   = h2 * KKH;

  int* f_own = flags + g * 64;
  const int* f_up = flags + (g > 0 ? (g - 1) * 64 : 0);
  const int* f_dn = flags + (g < 3 ? (g + 1) * 64 : 0);

  const int c16 = lane & 15;
  const int kg8 = (lane >> 4) * 8;
  const int rb0 = m2 * 32 + c16;   // A row for mt=0
  const int rb1 = rb0 + 16;        // A row for mt=1

  // ---- stationary gate-weight fragments (f16) ----
  // B-frag (kk,nt): lane holds W[n(nt,c16)][(kk0+kk)*32 + kg8 .. +7]
  // n ordering inside the 32-col slice: [i j0..j0+7 | f .. | g .. | o ..]
  half8 bw[16][2];
  #pragma unroll
  for (int kk2 = 0; kk2 < 16; ++kk2) {
    if (kk2 < KKH) {
      int kb = (kk0 + kk2) * 32 + kg8;
      #pragma unroll
      for (int nt = 0; nt < 2; ++nt) {
        int nl = nt * 16 + c16;
        int n  = (nl >> 3) * 512 + j0 + (nl & 7);
        const float* src = W + (size_t)n * fanin + kb;
        half8 r;
        #pragma unroll
        for (int e = 0; e < 8; ++e) r[e] = (_Float16)src[e];
        bw[kk2][nt] = r;
      }
    }
  }

  // ---- layer-3 extras: stationary Wo tile (f16), LN params, bias ----
  half8 wo16[16];
  float lng0 = 0.f, lng1 = 0.f, lnb0 = 0.f, lnb1 = 0.f, bo_v = 0.f;
  if (g == 3) {
    const int o = (wid << 4) + c16;          // wave's o-tile column
    #pragma unroll
    for (int kk = 0; kk < 16; ++kk) {
      const float* wp = Wo + (size_t)o * H_ + kk * 32 + kg8;
      half8 r;
      #pragma unroll
      for (int e = 0; e < 8; ++e) r[e] = (_Float16)wp[e];
      wo16[kk] = r;
    }
    lng0 = lng[2 * tid];  lng1 = lng[2 * tid + 1];
    lnb0 = lnb[2 * tid];  lnb1 = lnb[2 * tid + 1];
    bo_v = bo[o];
  }

  // ---- gate-phase constants: thread (gb = batch row, columns 2gj, 2gj+1) ----
  const int gb = tid & 63;
  const int gj = tid >> 6;          // 0..3 -> columns j0+2gj, j0+2gj+1
  const int jc = 2 * gj;
  const float bi0 = bias[0*512 + j0 + jc],     bf0 = bias[1*512 + j0 + jc];
  const float bg0 = bias[2*512 + j0 + jc],     bo0 = bias[3*512 + j0 + jc];
  const float bi1 = bias[0*512 + j0 + jc + 1], bf1 = bias[1*512 + j0 + jc + 1];
  const float bg1 = bias[2*512 + j0 + jc + 1], bo1 = bias[3*512 + j0 + jc + 1];
  float c0 = 0.f, c1 = 0.f;  // cell state stays in registers

  __shared__ float zl[64][33];
  __shared__ _Float16 hrow16[512];
  __shared__ float lnred[8];

  // ---- fused LN + proj slice: this block's batch row b = jblk, step t_ln ----
  auto ln_slice = [&](int t_ln) {
    const _Float16* hp = slab_ptr(hb, 3, t_ln) + (size_t)jblk * H_ + 2 * tid;
    union { uint32_t u; _Float16 h[2]; } hv;
    hv.u = __hip_atomic_load((const uint32_t*)hp, __ATOMIC_RELAXED,
                             __HIP_MEMORY_SCOPE_AGENT);
    float v0 = (float)hv.h[0], v1 = (float)hv.h[1];
    float s = v0 + v1, q = v0 * v0 + v1 * v1;
    #pragma unroll
    for (int d = 1; d < 64; d <<= 1) {
      s += __shfl_xor(s, d);
      q += __shfl_xor(q, d);
    }
    if (lane == 0) { lnred[wid * 2] = s; lnred[wid * 2 + 1] = q; }
    __syncthreads();
    float ss = lnred[0] + lnred[2] + lnred[4] + lnred[6];
    float qq = lnred[1] + lnred[3] + lnred[5] + lnred[7];
    float mu = ss * (1.f / 512.f);
    float rs = rsqrtf(qq * (1.f / 512.f) - mu * mu + 1e-5f);
    hrow16[2 * tid]     = (_Float16)((v0 - mu) * rs * lng0 + lnb0);
    hrow16[2 * tid + 1] = (_Float16)((v1 - mu) * rs * lng1 + lnb1);
    __syncthreads();
    // proj via MFMA: A row 0 = normalized h-row, other rows zero
    f32x4 pacc = {};
    #pragma unroll
    for (int kk = 0; kk < 16; ++kk) {
      half8 a = {};
      if (c16 == 0) a = *(const half8*)(hrow16 + kk * 32 + kg8);
      pacc = __builtin_amdgcn_mfma_f32_16x16x32_f16(a, wo16[kk], pacc, 0,0,0);
    }
    if (lane < 16) {   // D[0][c16] lives in lanes 0..15, reg 0
      out[((size_t)jblk * S_ + t_ln) * DOUT_ + (wid << 4) + lane]
          = pacc[0] + bo_v;
    }
  };

  for (int t = 0; t < S_; ++t) {
    f32x4 acc00 = {}, acc01 = {}, acc10 = {}, acc11 = {};

    if (g == 0) {
      if (t > 0) spin_ge(f_own, lane, t);
      const _Float16* hsl = slab_ptr(hb, 0, t - 1);
      half8 av0[9], av1[9];
      if (h2 == 0) {
        // kk 0,1 -> x (fp32, convert); kk 2..8 -> own h at hcol = kk*32-64
        #pragma unroll
        for (int kk2 = 0; kk2 < 2; ++kk2) {
          int kcol = kk2 * 32 + kg8;
          const float* xp0 = x + ((size_t)rb0 * S_ + t) * DIN_ + kcol;
          const float* xp1 = x + ((size_t)rb1 * S_ + t) * DIN_ + kcol;
          half8 a0, a1;
          #pragma unroll
          for (int e = 0; e < 8; ++e) {
            a0[e] = (_Float16)xp0[e]; a1[e] = (_Float16)xp1[e];
          }
          av0[kk2] = a0; av1[kk2] = a1;
        }
        #pragma unroll
        for (int kk2 = 2; kk2 < 9; ++kk2) {
          int hcol = kk2 * 32 + kg8 - 64;
          half8 a0 = {}, a1 = {};
          if (t > 0) {
            a0 = ld8c(hsl + (size_t)rb0 * H_ + hcol);
            a1 = ld8c(hsl + (size_t)rb1 * H_ + hcol);
          }
          av0[kk2] = a0; av1[kk2] = a1;
        }
      } else {
        #pragma unroll
        for (int kk2 = 0; kk2 < 9; ++kk2) {
          int hcol = (9 + kk2) * 32 + kg8 - 64;
          half8 a0 = {}, a1 = {};
          if (t > 0) {
            a0 = ld8c(hsl + (size_t)rb0 * H_ + hcol);
            a1 = ld8c(hsl + (size_t)rb1 * H_ + hcol);
          }
          av0[kk2] = a0; av1[kk2] = a1;
        }
      }
      #pragma unroll
      for (int kk2 = 0; kk2 < 9; ++kk2) {
        acc00 = __builtin_amdgcn_mfma_f32_16x16x32_f16(av0[kk2], bw[kk2][0], acc00, 0,0,0);
        acc01 = __builtin_amdgcn_mfma_f32_16x16x32_f16(av0[kk2], bw[kk2][1], acc01, 0,0,0);
        acc10 = __builtin_amdgcn_mfma_f32_16x16x32_f16(av1[kk2], bw[kk2][0], acc10, 0,0,0);
        acc11 = __builtin_amdgcn_mfma_f32_16x16x32_f16(av1[kk2], bw[kk2][1], acc11, 0,0,0);
      }
    } else {
      // h2=0 waves: upstream h^{g-1}[t]; h2=1: own h^g[t-1]
      if (h2 == 0) spin_ge(f_up, lane, t + 1);
      else if (t > 0) spin_ge(f_own, lane, t);
      const _Float16* src = (h2 == 0) ? slab_ptr(hb, g - 1, t)
                                      : slab_ptr(hb, g, t - 1);
      const bool zero = (h2 == 1) && (t == 0);
      half8 av0[16], av1[16];
      if (!zero) {
        #pragma unroll
        for (int kk2 = 0; kk2 < 16; ++kk2) {
          int kcol = kk2 * 32 + kg8;
          av0[kk2] = ld8c(src + (size_t)rb0 * H_ + kcol);
          av1[kk2] = ld8c(src + (size_t)rb1 * H_ + kcol);
        }
      } else {
        #pragma unroll
        for (int kk2 = 0; kk2 < 16; ++kk2) { av0[kk2] = {}; av1[kk2] = {}; }
      }
      #pragma unroll
      for (int kk2 = 0; kk2 < 16; ++kk2) {
        acc00 = __builtin_amdgcn_mfma_f32_16x16x32_f16(av0[kk2], bw[kk2][0], acc00, 0,0,0);
        acc01 = __builtin_amdgcn_mfma_f32_16x16x32_f16(av0[kk2], bw[kk2][1], acc01, 0,0,0);
        acc10 = __builtin_amdgcn_mfma_f32_16x16x32_f16(av1[kk2], bw[kk2][0], acc10, 0,0,0);
        acc11 = __builtin_amdgcn_mfma_f32_16x16x32_f16(av1[kk2], bw[kk2][1], acc11, 0,0,0);
      }
    }

    // ---- combine K-halves in LDS (C layout: col=lane&15, row=(lane>>4)*4+r)
    const int zr0 = m2 * 32 + (lane >> 4) * 4;
    if (h2 == 0) {
      #pragma unroll
      for (int r = 0; r < 4; ++r) {
        zl[zr0 + r][c16]            = acc00[r];
        zl[zr0 + r][16 + c16]       = acc01[r];
        zl[zr0 + 16 + r][c16]       = acc10[r];
        zl[zr0 + 16 + r][16 + c16]  = acc11[r];
      }
    }
    __syncthreads();
    if (h2 == 1) {
      #pragma unroll
      for (int r = 0; r < 4; ++r) {
        zl[zr0 + r][c16]            += acc00[r];
        zl[zr0 + r][16 + c16]       += acc01[r];
        zl[zr0 + 16 + r][c16]       += acc10[r];
        zl[zr0 + 16 + r][16 + c16]  += acc11[r];
      }
    }
    // ring back-pressure: don't overwrite slot t%16 until downstream did t-16
    if (g < 3 && t >= RING_) spin_ge(f_dn, lane, t - (RING_ - 1));
    __syncthreads();

    // ---- gates + cell update (fp32); 2 adjacent h cols -> one dword ----
    _Float16* osl = slab_ptr(hb, g, t);
    {
      float zi = zl[gb][jc]          + bi0;
      float zf = zl[gb][8 + jc]      + bf0;
      float zg = zl[gb][16 + jc]     + bg0;
      float zo = zl[gb][24 + jc]     + bo0;
      float cc = sigm(zf) * c0 + sigm(zi) * tanh_(zg);
      c0 = cc;
      float h0 = sigm(zo) * tanh_(cc);

      zi = zl[gb][jc + 1]      + bi1;
      zf = zl[gb][8 + jc + 1]  + bf1;
      zg = zl[gb][16 + jc + 1] + bg1;
      zo = zl[gb][24 + jc + 1] + bo1;
      cc = sigm(zf) * c1 + sigm(zi) * tanh_(zg);
      c1 = cc;
      float h1 = sigm(zo) * tanh_(cc);

      union { uint32_t u; _Float16 h[2]; } pk;
      pk.h[0] = (_Float16)h0; pk.h[1] = (_Float16)h1;
      __hip_atomic_store((uint32_t*)(osl + (size_t)gb * H_ + j0 + jc), pk.u,
                         __ATOMIC_RELAXED, __HIP_MEMORY_SCOPE_AGENT);
    }
    __syncthreads();  // drains vmcnt(0) in every thread -> h[t] at LLC
    if (tid == 0) {
      __hip_atomic_store(&f_own[jblk], t + 1, __ATOMIC_RELAXED,
                         __HIP_MEMORY_SCOPE_AGENT);
    }

    // ---- fused LN + proj for step t-1 (layer-3 blocks, own batch row) ----
    // Ring safety: slot (t-1)&15 first overwritten at iteration t+15, whose
    // own-layer spin (flags >= t+15) implies every block's iteration t
    // (hence its ln_slice(t-1)) completed.
    if (g == 3 && t >= 1) ln_slice(t - 1);
  }

  if (g == 3) {           // final step's LN+proj
    spin_ge(f_own, lane, S_);
    ln_slice(S_ - 1);
  }
}

extern "C" void kernel_launch(void* const* d_in, const int* in_sizes, int n_in,
                              void* d_out, int out_size, void* d_ws, size_t ws_size,
                              hipStream_t stream) {
  const float* x   = (const float*)d_in[0];
  const float* W0  = (const float*)d_in[1];
  const float* b0  = (const float*)d_in[2];
  const float* W1  = (const float*)d_in[3];
  const float* b1  = (const float*)d_in[4];
  const float* W2  = (const float*)d_in[5];
  const float* b2  = (const float*)d_in[6];
  const float* W3  = (const float*)d_in[7];
  const float* b3  = (const float*)d_in[8];
  const float* lng = (const float*)d_in[9];
  const float* lnb = (const float*)d_in[10];
  const float* Wo  = (const float*)d_in[11];
  const float* bo  = (const float*)d_in[12];
  float* out = (float*)d_out;

  int* flags = (int*)d_ws;                          // [4][64] step flags
  _Float16* hb = (_Float16*)((char*)d_ws + 4096);   // 4 x 16-slot rings, 4MB

  hipMemsetAsync(flags, 0, 4096, stream);
  hipLaunchKernelGGL(lstm_fused, dim3(256), dim3(256), 0, stream,
                     x, W0, b0, W1, b1, W2, b2, W3, b3,
                     lng, lnb, Wo, bo, flags, hb, out);
}

// Round 5
// 3354.635 us; speedup vs baseline: 4.8547x; 3.2035x over previous
//
#include <hip/hip_runtime.h>
#include <stdint.h>

// 4-layer LSTM (B=64,S=512,H=512) + LayerNorm + proj(512->64), fp32 in/out.
// v4: kill LLC poll-storm + transaction amplification.
//  - v3 (10.7ms, bimodal 51ms outliers, WRITE_SIZE 1.06GB): (a) 64-flag spin
//    gathers by ~768 waves every ~50ns = TB/s of sc1 poll traffic at the LLC;
//    (b) ld8c = 4 dword atomics, lanes stride 1-2KB -> 32-64 partial-line
//    transactions per load instr; h-stores quarter-density.
//  - v4: (1) FRAGMENT-NATIVE ring layout [kk][r16][kg][ri][e8]: wave A-frag
//    reads are dense 1KB/instr; gate threads remapped (gb=wid*16+lane/4,
//    jc=(lane&3)*2) so h-stores are dense 256B/wave runs. (2) ld8c = 2x
//    uint64 agent atomic loads (global_load_dwordx2 sc1, compiler-pipelined).
//    (3) per-layer COUNTER sync: producers fetch_add once per step; consumers
//    spin on ONE uniform dword (ctr[g] >= 64*t). Poll payload 64x down.
//  - Structure unchanged: 256 blocks x 256 thr; block=(layer g, 8-col slice);
//    f16 weights stationary in registers; waves split K (h2) x M (m2);
//    16-step rings (4.2MB ws); LN+proj fused into layer-3 blocks by batch row.

#define B_    64
#define S_    512
#define DIN_  64
#define H_    512
#define DOUT_ 64
#define RING_ 16

typedef _Float16 half8 __attribute__((ext_vector_type(8)));
typedef float    f32x4 __attribute__((ext_vector_type(4)));

__device__ __forceinline__ float sigm(float x) {
  return 1.0f / (1.0f + exp2f(-1.4426950408889634f * x));
}
__device__ __forceinline__ float tanh_(float x) {
  float e = exp2f(2.8853900817779268f * x);
  return 1.0f - 2.0f / (e + 1.0f);
}

// 16-deep ring slab for every layer (fragment-native internal order):
// element (row r, col c) at kk*2048 + (r>>4)*512 + ((c>>3)&3)*128 + (r&15)*8
// + (c&7), kk = c>>5.  One tile = 32768 halves = 64KB.
__device__ __forceinline__ _Float16* slab_ptr(_Float16* hb, int l, int t) {
  return hb + ((size_t)l * RING_ + (size_t)(t & (RING_ - 1))) * (size_t)(B_ * H_);
}

// coherent (LLC) 16B load as 2 agent-scope relaxed atomic qwords
__device__ __forceinline__ half8 ld8c(const _Float16* p) {
  const uint64_t* q = (const uint64_t*)p;
  union { uint64_t u[2]; half8 v; } r;
  r.u[0] = __hip_atomic_load(q,     __ATOMIC_RELAXED, __HIP_MEMORY_SCOPE_AGENT);
  r.u[1] = __hip_atomic_load(q + 1, __ATOMIC_RELAXED, __HIP_MEMORY_SCOPE_AGENT);
  return r.v;
}

// spin until *c >= val (uniform address, 4B poll)
__device__ __forceinline__ void spin_ctr(const int* c, int val) {
  for (;;) {
    int v = __hip_atomic_load((int*)c, __ATOMIC_RELAXED,
                              __HIP_MEMORY_SCOPE_AGENT);
    if (v >= val) break;
    __builtin_amdgcn_s_sleep(1);
  }
  __builtin_amdgcn_sched_barrier(0);   // keep data loads below the spin
}

__global__ __launch_bounds__(256, 1)
void lstm_fused(const float* __restrict__ x,
                const float* __restrict__ Wl0, const float* __restrict__ bl0,
                const float* __restrict__ Wl1, const float* __restrict__ bl1,
                const float* __restrict__ Wl2, const float* __restrict__ bl2,
                const float* __restrict__ Wl3, const float* __restrict__ bl3,
                const float* __restrict__ lng, const float* __restrict__ lnb,
                const float* __restrict__ Wo,  const float* __restrict__ bo,
                int* __restrict__ ctr, _Float16* __restrict__ hb,
                float* __restrict__ out)
{
  const int tid  = threadIdx.x;
  const int lane = tid & 63;
  const int wid  = tid >> 6;
  const int m2   = wid & 1;   // M half (rows m2*32..m2*32+31)
  const int h2   = wid >> 1;  // K half
  const int bid  = blockIdx.x;
  const int g    = bid & 3;   // layer
  const int jblk = bid >> 2;  // 0..63
  const int j0   = jblk * 8;  // h-column slice base

  const float* W    = (g==0)?Wl0:(g==1)?Wl1:(g==2)?Wl2:Wl3;
  const float* bias = (g==0)?bl0:(g==1)?bl1:(g==2)?bl2:bl3;
  const int fanin = (g == 0) ? (DIN_ + H_) : (2 * H_);
  const int KKH   = (g == 0) ? 9 : 16;   // K/32 chunks per wave-half
  const int kk0   = h2 * KKH;

  const int c16 = lane & 15;
  const int kg8 = (lane >> 4) * 8;
  const int rb0 = m2 * 32 + c16;   // A row for mt=0 (x loads only)
  const int rb1 = rb0 + 16;        // A row for mt=1

  // ---- stationary gate-weight fragments (f16) ----
  // B-frag (kk,nt): lane holds W[n(nt,c16)][(kk0+kk)*32 + kg8 .. +7]
  // n ordering inside the 32-col slice: [i j0..j0+7 | f .. | g .. | o ..]
  half8 bw[16][2];
  #pragma unroll
  for (int kk2 = 0; kk2 < 16; ++kk2) {
    if (kk2 < KKH) {
      int kb = (kk0 + kk2) * 32 + kg8;
      #pragma unroll
      for (int nt = 0; nt < 2; ++nt) {
        int nl = nt * 16 + c16;
        int n  = (nl >> 3) * 512 + j0 + (nl & 7);
        const float* src = W + (size_t)n * fanin + kb;
        half8 r;
        #pragma unroll
        for (int e = 0; e < 8; ++e) r[e] = (_Float16)src[e];
        bw[kk2][nt] = r;
      }
    }
  }

  // ---- layer-3 extras: stationary Wo tile (f16), LN params, bias ----
  half8 wo16[16];
  float lng0 = 0.f, lng1 = 0.f, lnb0 = 0.f, lnb1 = 0.f, bo_v = 0.f;
  if (g == 3) {
    const int o = (wid << 4) + c16;          // wave's o-tile column
    #pragma unroll
    for (int kk = 0; kk < 16; ++kk) {
      const float* wp = Wo + (size_t)o * H_ + kk * 32 + kg8;
      half8 r;
      #pragma unroll
      for (int e = 0; e < 8; ++e) r[e] = (_Float16)wp[e];
      wo16[kk] = r;
    }
    lng0 = lng[2 * tid];  lng1 = lng[2 * tid + 1];
    lnb0 = lnb[2 * tid];  lnb1 = lnb[2 * tid + 1];
    bo_v = bo[o];
  }

  // ---- gate-phase mapping: thread -> (row gb, col pair j0+jc, j0+jc+1)
  // chosen so each wave's h-store is a DENSE 256B run in fragment layout.
  const int gb = (wid << 4) | (lane >> 2);   // 0..63
  const int jc = (lane & 3) * 2;             // 0,2,4,6
  const float bi0 = bias[0*512 + j0 + jc],     bf0 = bias[1*512 + j0 + jc];
  const float bg0 = bias[2*512 + j0 + jc],     bo0 = bias[3*512 + j0 + jc];
  const float bi1 = bias[0*512 + j0 + jc + 1], bf1 = bias[1*512 + j0 + jc + 1];
  const float bg1 = bias[2*512 + j0 + jc + 1], bo1 = bias[3*512 + j0 + jc + 1];
  float c0 = 0.f, c1 = 0.f;  // cell state stays in registers
  // h-store offset in fragment layout (halves); dword-aligned (jc even)
  const size_t hoff = (size_t)(jblk >> 2) * 2048 + (size_t)wid * 512
                    + (size_t)(jblk & 3) * 128 + (size_t)(lane >> 2) * 8 + jc;

  __shared__ float zl[64][33];
  __shared__ _Float16 hrow16[512];
  __shared__ float lnred[8];

  // ---- fused LN + proj slice: this block's batch row b = jblk, step t_ln ----
  auto ln_slice = [&](int t_ln) {
    // cols 2*tid, 2*tid+1 of row jblk in fragment layout
    const size_t loff = (size_t)(tid >> 4) * 2048 + (size_t)(jblk >> 4) * 512
                      + (size_t)((tid >> 2) & 3) * 128
                      + (size_t)(jblk & 15) * 8 + ((2 * tid) & 7);
    const _Float16* hp = slab_ptr(hb, 3, t_ln) + loff;
    union { uint32_t u; _Float16 h[2]; } hv;
    hv.u = __hip_atomic_load((const uint32_t*)hp, __ATOMIC_RELAXED,
                             __HIP_MEMORY_SCOPE_AGENT);
    float v0 = (float)hv.h[0], v1 = (float)hv.h[1];
    float s = v0 + v1, q = v0 * v0 + v1 * v1;
    #pragma unroll
    for (int d = 1; d < 64; d <<= 1) {
      s += __shfl_xor(s, d);
      q += __shfl_xor(q, d);
    }
    if (lane == 0) { lnred[wid * 2] = s; lnred[wid * 2 + 1] = q; }
    __syncthreads();
    float ss = lnred[0] + lnred[2] + lnred[4] + lnred[6];
    float qq = lnred[1] + lnred[3] + lnred[5] + lnred[7];
    float mu = ss * (1.f / 512.f);
    float rs = rsqrtf(qq * (1.f / 512.f) - mu * mu + 1e-5f);
    hrow16[2 * tid]     = (_Float16)((v0 - mu) * rs * lng0 + lnb0);
    hrow16[2 * tid + 1] = (_Float16)((v1 - mu) * rs * lng1 + lnb1);
    __syncthreads();
    // proj via MFMA: A row 0 = normalized h-row, other rows zero
    f32x4 pacc = {};
    #pragma unroll
    for (int kk = 0; kk < 16; ++kk) {
      half8 a = {};
      if (c16 == 0) a = *(const half8*)(hrow16 + kk * 32 + kg8);
      pacc = __builtin_amdgcn_mfma_f32_16x16x32_f16(a, wo16[kk], pacc, 0,0,0);
    }
    if (lane < 16) {   // D[0][c16] lives in lanes 0..15, reg 0
      out[((size_t)jblk * S_ + t_ln) * DOUT_ + (wid << 4) + lane]
          = pacc[0] + bo_v;
    }
  };

  for (int t = 0; t < S_; ++t) {
    f32x4 acc00 = {}, acc01 = {}, acc10 = {}, acc11 = {};

    if (g == 0) {
      half8 av0[9], av1[9];
      if (h2 == 0) {
        // x loads (external input, always ready) BEFORE the spin
        #pragma unroll
        for (int kk2 = 0; kk2 < 2; ++kk2) {
          int kcol = kk2 * 32 + kg8;
          const float* xp0 = x + ((size_t)rb0 * S_ + t) * DIN_ + kcol;
          const float* xp1 = x + ((size_t)rb1 * S_ + t) * DIN_ + kcol;
          half8 a0, a1;
          #pragma unroll
          for (int e = 0; e < 8; ++e) {
            a0[e] = (_Float16)xp0[e]; a1[e] = (_Float16)xp1[e];
          }
          av0[kk2] = a0; av1[kk2] = a1;
        }
      }
      if (t > 0) spin_ctr(ctr, 64 * t);
      const _Float16* base = slab_ptr(hb, 0, t - 1) + m2 * 1024 + lane * 8;
      if (h2 == 0) {
        #pragma unroll
        for (int kk2 = 2; kk2 < 9; ++kk2) {
          half8 a0 = {}, a1 = {};
          if (t > 0) {
            a0 = ld8c(base + (kk2 - 2) * 2048);
            a1 = ld8c(base + (kk2 - 2) * 2048 + 512);
          }
          av0[kk2] = a0; av1[kk2] = a1;
        }
      } else {
        #pragma unroll
        for (int kk2 = 0; kk2 < 9; ++kk2) {
          half8 a0 = {}, a1 = {};
          if (t > 0) {
            a0 = ld8c(base + (kk2 + 7) * 2048);
            a1 = ld8c(base + (kk2 + 7) * 2048 + 512);
          }
          av0[kk2] = a0; av1[kk2] = a1;
        }
      }
      #pragma unroll
      for (int kk2 = 0; kk2 < 9; ++kk2) {
        acc00 = __builtin_amdgcn_mfma_f32_16x16x32_f16(av0[kk2], bw[kk2][0], acc00, 0,0,0);
        acc01 = __builtin_amdgcn_mfma_f32_16x16x32_f16(av0[kk2], bw[kk2][1], acc01, 0,0,0);
        acc10 = __builtin_amdgcn_mfma_f32_16x16x32_f16(av1[kk2], bw[kk2][0], acc10, 0,0,0);
        acc11 = __builtin_amdgcn_mfma_f32_16x16x32_f16(av1[kk2], bw[kk2][1], acc11, 0,0,0);
      }
    } else {
      // h2=0 waves: upstream h^{g-1}[t]; h2=1: own h^g[t-1]
      if (h2 == 0) spin_ctr(ctr + (g - 1), 64 * (t + 1));
      else if (t > 0) spin_ctr(ctr + g, 64 * t);
      const _Float16* src = (h2 == 0) ? slab_ptr(hb, g - 1, t)
                                      : slab_ptr(hb, g, t - 1);
      const _Float16* base = src + m2 * 1024 + lane * 8;
      const bool zero = (h2 == 1) && (t == 0);
      half8 av0[16], av1[16];
      if (!zero) {
        #pragma unroll
        for (int kk2 = 0; kk2 < 16; ++kk2) {
          av0[kk2] = ld8c(base + kk2 * 2048);
          av1[kk2] = ld8c(base + kk2 * 2048 + 512);
        }
      } else {
        #pragma unroll
        for (int kk2 = 0; kk2 < 16; ++kk2) { av0[kk2] = {}; av1[kk2] = {}; }
      }
      #pragma unroll
      for (int kk2 = 0; kk2 < 16; ++kk2) {
        acc00 = __builtin_amdgcn_mfma_f32_16x16x32_f16(av0[kk2], bw[kk2][0], acc00, 0,0,0);
        acc01 = __builtin_amdgcn_mfma_f32_16x16x32_f16(av0[kk2], bw[kk2][1], acc01, 0,0,0);
        acc10 = __builtin_amdgcn_mfma_f32_16x16x32_f16(av1[kk2], bw[kk2][0], acc10, 0,0,0);
        acc11 = __builtin_amdgcn_mfma_f32_16x16x32_f16(av1[kk2], bw[kk2][1], acc11, 0,0,0);
      }
    }

    // ---- combine K-halves in LDS (C layout: col=lane&15, row=(lane>>4)*4+r)
    const int zr0 = m2 * 32 + (lane >> 4) * 4;
    if (h2 == 0) {
      #pragma unroll
      for (int r = 0; r < 4; ++r) {
        zl[zr0 + r][c16]            = acc00[r];
        zl[zr0 + r][16 + c16]       = acc01[r];
        zl[zr0 + 16 + r][c16]       = acc10[r];
        zl[zr0 + 16 + r][16 + c16]  = acc11[r];
      }
    }
    __syncthreads();
    if (h2 == 1) {
      #pragma unroll
      for (int r = 0; r < 4; ++r) {
        zl[zr0 + r][c16]            += acc00[r];
        zl[zr0 + r][16 + c16]       += acc01[r];
        zl[zr0 + 16 + r][c16]       += acc10[r];
        zl[zr0 + 16 + r][16 + c16]  += acc11[r];
      }
    }
    // ring back-pressure: don't overwrite slot t%16 until downstream did t-16
    if (g < 3 && t >= RING_) spin_ctr(ctr + (g + 1), 64 * (t - 15));
    __syncthreads();

    // ---- gates + cell update (fp32); 2 adjacent h cols -> one dword ----
    _Float16* osl = slab_ptr(hb, g, t);
    {
      float zi = zl[gb][jc]          + bi0;
      float zf = zl[gb][8 + jc]      + bf0;
      float zg = zl[gb][16 + jc]     + bg0;
      float zo = zl[gb][24 + jc]     + bo0;
      float cc = sigm(zf) * c0 + sigm(zi) * tanh_(zg);
      c0 = cc;
      float h0 = sigm(zo) * tanh_(cc);

      zi = zl[gb][jc + 1]      + bi1;
      zf = zl[gb][8 + jc + 1]  + bf1;
      zg = zl[gb][16 + jc + 1] + bg1;
      zo = zl[gb][24 + jc + 1] + bo1;
      cc = sigm(zf) * c1 + sigm(zi) * tanh_(zg);
      c1 = cc;
      float h1 = sigm(zo) * tanh_(cc);

      union { uint32_t u; _Float16 h[2]; } pk;
      pk.h[0] = (_Float16)h0; pk.h[1] = (_Float16)h1;
      __hip_atomic_store((uint32_t*)(osl + hoff), pk.u,
                         __ATOMIC_RELAXED, __HIP_MEMORY_SCOPE_AGENT);
    }
    __syncthreads();  // drains vmcnt(0) in every wave -> h[t] at LLC
    if (tid == 0) {
      __hip_atomic_fetch_add(ctr + g, 1, __ATOMIC_RELAXED,
                             __HIP_MEMORY_SCOPE_AGENT);
    }

    // ---- fused LN + proj for step t-1 (layer-3 blocks, own batch row) ----
    // Ready: h2=1 spin this iter saw ctr[3] >= 64t (peers wrote h3[t-1]).
    // Slot (t-1)&15 overwritten first at iter t+15, gated on ctr[3] >=
    // 64*(t+15) which implies every block finished iter t+14 > this slice.
    if (g == 3 && t >= 1) ln_slice(t - 1);
  }

  if (g == 3) {           // final step's LN+proj
    spin_ctr(ctr + 3, 64 * S_);
    ln_slice(S_ - 1);
  }
}

extern "C" void kernel_launch(void* const* d_in, const int* in_sizes, int n_in,
                              void* d_out, int out_size, void* d_ws, size_t ws_size,
                              hipStream_t stream) {
  const float* x   = (const float*)d_in[0];
  const float* W0  = (const float*)d_in[1];
  const float* b0  = (const float*)d_in[2];
  const float* W1  = (const float*)d_in[3];
  const float* b1  = (const float*)d_in[4];
  const float* W2  = (const float*)d_in[5];
  const float* b2  = (const float*)d_in[6];
  const float* W3  = (const float*)d_in[7];
  const float* b3  = (const float*)d_in[8];
  const float* lng = (const float*)d_in[9];
  const float* lnb = (const float*)d_in[10];
  const float* Wo  = (const float*)d_in[11];
  const float* bo  = (const float*)d_in[12];
  float* out = (float*)d_out;

  int* ctr = (int*)d_ws;                            // [4] step counters
  _Float16* hb = (_Float16*)((char*)d_ws + 4096);   // 4 x 16-slot rings, 4MB

  hipMemsetAsync(ctr, 0, 4096, stream);
  hipLaunchKernelGGL(lstm_fused, dim3(256), dim3(256), 0, stream,
                     x, W0, b0, W1, b1, W2, b2, W3, b3,
                     lng, lnb, Wo, bo, ctr, hb, out);
}